// Round 2
// baseline (1080.446 us; speedup 1.0000x reference)
//
#include <hip/hip_runtime.h>

typedef __bf16 bf16;
typedef bf16 bf16x8 __attribute__((ext_vector_type(8)));
typedef float f32x4 __attribute__((ext_vector_type(4)));

#define NPIX 196
#define CIN 384
#define NHEADS 12
#define MPAD 224

// flag-aware scalar load: f=1 -> fp32 data, f=0 -> bf16 data
__device__ __forceinline__ float ldf(const void* p, size_t i, int f) {
    return f ? ((const float*)p)[i] : (float)((const bf16*)p)[i];
}

// ---------------- dtype detector ----------------
// Reads 2048 32-bit words of x. Interprets the LOW 16 bits of each word as a
// bf16 and checks its exponent field. bf16-of-N(0,1) data: exp <= ~134.
// fp32 data: low 16 bits are mantissa junk -> ~21% have exp > 200.
__global__ void detect_kernel(const unsigned int* __restrict__ x, int* __restrict__ flag) {
    __shared__ int cnt;
    if (threadIdx.x == 0) cnt = 0;
    __syncthreads();
    int c = 0;
#pragma unroll
    for (int k = 0; k < 8; k++) {
        unsigned int w = x[threadIdx.x * 8 + k];
        unsigned int e = (w >> 7) & 0xFFu;
        if (e > 200u) c++;
    }
    atomicAdd(&cnt, c);
    __syncthreads();
    if (threadIdx.x == 0) *flag = (cnt >= 16) ? 1 : 0;
}

// ---------------- canonicalize weights to bf16 ----------------
__global__ void convert_kernel(const void* __restrict__ src, bf16* __restrict__ dst, int n,
                               const int* __restrict__ flag) {
    int f = *flag;
    for (int i = blockIdx.x * 256 + threadIdx.x; i < n; i += gridDim.x * 256)
        dst[i] = (bf16)ldf(src, i, f);
}

// ---------------- transpose x: (b, c, hw) -> (b, hw, c), canonical bf16 ----------------
__global__ void transpose_x_kernel(const void* __restrict__ x, const int* __restrict__ flag,
                                   bf16* __restrict__ xt, int b0) {
    __shared__ bf16 tile[32][33];
    int f = *flag;
    int b = blockIdx.z, gb = b0 + b;
    int c0 = blockIdx.y * 32;
    int hw0 = blockIdx.x * 32;
    int tx = threadIdx.x, ty = threadIdx.y;
    int hw = hw0 + tx, c = c0 + ty;
    if (hw < NPIX) tile[ty][tx] = (bf16)ldf(x, ((size_t)gb * CIN + c) * NPIX + hw, f);
    __syncthreads();
    int hw2 = hw0 + ty, c2 = c0 + tx;
    if (hw2 < NPIX) xt[((size_t)b * NPIX + hw2) * CIN + c2] = tile[tx][ty];
}

// ---------------- QKV GEMM + BN, routed outputs ----------------
__global__ __launch_bounds__(256) void gemm_qkv_kernel(
    const bf16* __restrict__ xt, const bf16* __restrict__ w,
    const void* __restrict__ g, const void* __restrict__ bb,
    const void* __restrict__ mm, const void* __restrict__ vv, const int* __restrict__ flag,
    bf16* __restrict__ qb, bf16* __restrict__ kt, bf16* __restrict__ vb) {
    int f = *flag;
    int b = blockIdx.y;
    int wave = threadIdx.x >> 6, lane = threadIdx.x & 63;
    int o0 = (blockIdx.x * 4 + wave) * 16;
    int row = lane & 15, grp = lane >> 4;
    f32x4 acc[13];
#pragma unroll
    for (int i = 0; i < 13; i++) acc[i] = (f32x4){0.f, 0.f, 0.f, 0.f};
    const bf16* arow = w + (size_t)(o0 + row) * CIN + grp * 8;
    const bf16* xb = xt + (size_t)b * NPIX * CIN + grp * 8;
    for (int kk = 0; kk < 12; kk++) {
        bf16x8 af = *(const bf16x8*)(arow + kk * 32);
#pragma unroll
        for (int nt = 0; nt < 13; nt++) {
            int col = nt * 16 + row;
            if (col > 195) col = 195;
            bf16x8 bfv = *(const bf16x8*)(xb + (size_t)col * CIN + kk * 32);
            acc[nt] = __builtin_amdgcn_mfma_f32_16x16x32_bf16(af, bfv, acc[nt], 0, 0, 0);
        }
    }
#pragma unroll
    for (int r = 0; r < 4; r++) {
        int o = o0 + grp * 4 + r;
        float sc = ldf(g, o, f) * rsqrtf(ldf(vv, o, f) + 1e-5f);
        float sh = ldf(bb, o, f) - ldf(mm, o, f) * sc;
#pragma unroll
        for (int nt = 0; nt < 13; nt++) {
            int col = nt * 16 + row;
            if (col >= NPIX) continue;
            float val = acc[nt][r] * sc + sh;
            bf16 bv = (bf16)val;
            if (o < 384) {
                qb[((size_t)b * 384 + o) * NPIX + col] = bv;
            } else if (o < 768) {
                kt[((size_t)b * NPIX + col) * 384 + (o - 384)] = bv;
            } else {
                vb[((size_t)b * 1536 + (o - 768)) * MPAD + col] = bv;
            }
        }
    }
}

// ---------------- depthwise 3x3 conv + BN, write transposed (b, hw, c) ----------------
__global__ void dwconv_kernel(const bf16* __restrict__ qb, const bf16* __restrict__ w,
                              const void* __restrict__ g, const void* __restrict__ bb,
                              const void* __restrict__ mm, const void* __restrict__ vv,
                              const int* __restrict__ flag, bf16* __restrict__ qt) {
    __shared__ bf16 tile[32][33];
    int f = *flag;
    int b = blockIdx.z;
    int c0 = blockIdx.y * 32, hw0 = blockIdx.x * 32;
    int tx = threadIdx.x, ty = threadIdx.y;
    int c = c0 + ty, hw = hw0 + tx;
    if (hw < NPIX) {
        int y = hw / 14, x = hw % 14;
        float acc = 0.f;
        const bf16* wp = w + c * 9;
        const bf16* qp = qb + ((size_t)b * 384 + c) * NPIX;
#pragma unroll
        for (int ky = 0; ky < 3; ky++) {
            int yy = y + ky - 1;
            if (yy < 0 || yy >= 14) continue;
#pragma unroll
            for (int kx = 0; kx < 3; kx++) {
                int xx = x + kx - 1;
                if (xx < 0 || xx >= 14) continue;
                acc += (float)qp[yy * 14 + xx] * (float)wp[ky * 3 + kx];
            }
        }
        float sc = ldf(g, c, f) * rsqrtf(ldf(vv, c, f) + 1e-5f);
        float sh = ldf(bb, c, f) - ldf(mm, c, f) * sc;
        tile[ty][tx] = (bf16)(acc * sc + sh);
    }
    __syncthreads();
    int hw2 = hw0 + ty, c2 = c0 + tx;
    if (hw2 < NPIX) qt[((size_t)b * NPIX + hw2) * CIN + c2] = tile[tx][ty];
}

// ---------------- bias gather: (12,196,196) fp32 ----------------
__global__ void bias_gather_kernel(const void* __restrict__ ab, const int* __restrict__ idx,
                                   const int* __restrict__ flag, float* __restrict__ biasf) {
    int f = *flag;
    int t = blockIdx.x * 256 + threadIdx.x;
    if (t >= NHEADS * NPIX * NPIX) return;
    int h = t / (NPIX * NPIX);
    int rem = t - h * (NPIX * NPIX);
    biasf[t] = ldf(ab, h * NPIX + idx[rem], f);
}

// ---------------- attention per (b,h) ----------------
__global__ __launch_bounds__(256) void attn_kernel(
    const bf16* __restrict__ qt, const bf16* __restrict__ ktp, const bf16* __restrict__ vb,
    const float* __restrict__ biasf, bf16* __restrict__ ot) {
    __shared__ bf16 Ksh[MPAD * 32];
    __shared__ bf16 Pw[4][16 * MPAD];
    int h = blockIdx.x, b = blockIdx.y;
    int tid = threadIdx.x;
    int wave = tid >> 6, lane = tid & 63;
    int row = lane & 15, grp = lane >> 4;
    {
        int mrow = tid >> 2, chunk = tid & 3;
#pragma unroll
        for (int p = 0; p < 4; p++) {
            int mth = p * 64 + mrow;
            if (mth < NPIX) {
                *(bf16x8*)(Ksh + mth * 32 + chunk * 8) =
                    *(const bf16x8*)(ktp + ((size_t)b * NPIX + mth) * CIN + h * 32 + chunk * 8);
            } else if (mth < MPAD) {
                bf16x8 z;
#pragma unroll
                for (int i = 0; i < 8; i++) z[i] = (bf16)0.f;
                *(bf16x8*)(Ksh + mth * 32 + chunk * 8) = z;
            }
        }
    }
    __syncthreads();
    const float scale = 0.17677669529663687f;
    f32x4 zf = {0.f, 0.f, 0.f, 0.f};
    for (int nb = wave; nb < 13; nb += 4) {
        int n0 = nb * 16;
        int qrow = n0 + row;
        if (qrow > 195) qrow = 195;
        bf16x8 aq = *(const bf16x8*)(qt + ((size_t)b * NPIX + qrow) * CIN + h * 32 + grp * 8);
        f32x4 sacc[14];
#pragma unroll
        for (int mt = 0; mt < 14; mt++) {
            bf16x8 bk = *(const bf16x8*)(Ksh + (mt * 16 + row) * 32 + grp * 8);
            sacc[mt] = __builtin_amdgcn_mfma_f32_16x16x32_bf16(aq, bk, zf, 0, 0, 0);
        }
#pragma unroll
        for (int r = 0; r < 4; r++) {
            int n = n0 + grp * 4 + r;
            int nc = n > 195 ? 195 : n;
            const float* bp = biasf + ((size_t)h * NPIX + nc) * NPIX;
            float sv[14];
            float mx = -3.4e38f;
#pragma unroll
            for (int mt = 0; mt < 14; mt++) {
                int col = mt * 16 + row;
                float bias = (col < NPIX) ? bp[col] : -3.0e38f;
                float s = sacc[mt][r] * scale + bias;
                sv[mt] = s;
                mx = fmaxf(mx, s);
            }
            mx = fmaxf(mx, __shfl_xor(mx, 1));
            mx = fmaxf(mx, __shfl_xor(mx, 2));
            mx = fmaxf(mx, __shfl_xor(mx, 4));
            mx = fmaxf(mx, __shfl_xor(mx, 8));
            float sum = 0.f;
#pragma unroll
            for (int mt = 0; mt < 14; mt++) {
                float e = __expf(sv[mt] - mx);
                sv[mt] = e;
                sum += e;
            }
            sum += __shfl_xor(sum, 1);
            sum += __shfl_xor(sum, 2);
            sum += __shfl_xor(sum, 4);
            sum += __shfl_xor(sum, 8);
            float inv = 1.f / sum;
#pragma unroll
            for (int mt = 0; mt < 14; mt++) {
                Pw[wave][(grp * 4 + r) * MPAD + mt * 16 + row] = (bf16)(sv[mt] * inv);
            }
        }
        f32x4 oacc[8];
#pragma unroll
        for (int dt = 0; dt < 8; dt++) oacc[dt] = zf;
#pragma unroll
        for (int kt = 0; kt < 7; kt++) {
            bf16x8 ap = *(const bf16x8*)(&Pw[wave][row * MPAD + kt * 32 + grp * 8]);
#pragma unroll
            for (int dt = 0; dt < 8; dt++) {
                bf16x8 bv = *(const bf16x8*)(vb + ((size_t)b * 1536 + h * 128 + dt * 16 + row) * MPAD +
                                             kt * 32 + grp * 8);
                oacc[dt] = __builtin_amdgcn_mfma_f32_16x16x32_bf16(ap, bv, oacc[dt], 0, 0, 0);
            }
        }
#pragma unroll
        for (int dt = 0; dt < 8; dt++) {
#pragma unroll
            for (int r = 0; r < 4; r++) {
                int n = n0 + grp * 4 + r;
                if (n < NPIX) {
                    float val = oacc[dt][r];
                    val = val > 0.f ? val : 0.f;
                    ot[((size_t)b * NPIX + n) * 1536 + h * 128 + dt * 16 + row] = (bf16)val;
                }
            }
        }
    }
}

// ---------------- proj GEMM + BN -> output (dtype per flag) ----------------
__global__ __launch_bounds__(256) void gemm_proj_kernel(
    const bf16* __restrict__ ot, const bf16* __restrict__ w,
    const void* __restrict__ g, const void* __restrict__ bb,
    const void* __restrict__ mm, const void* __restrict__ vv, const int* __restrict__ flag,
    void* __restrict__ out, int b0) {
    int f = *flag;
    int b = blockIdx.y, gb = b0 + b;
    int wave = threadIdx.x >> 6, lane = threadIdx.x & 63;
    int o0 = (blockIdx.x * 4 + wave) * 16;
    int row = lane & 15, grp = lane >> 4;
    f32x4 acc[13];
#pragma unroll
    for (int i = 0; i < 13; i++) acc[i] = (f32x4){0.f, 0.f, 0.f, 0.f};
    const bf16* arow = w + (size_t)(o0 + row) * 1536 + grp * 8;
    const bf16* xb = ot + (size_t)b * NPIX * 1536 + grp * 8;
    for (int kk = 0; kk < 48; kk++) {
        bf16x8 af = *(const bf16x8*)(arow + kk * 32);
#pragma unroll
        for (int nt = 0; nt < 13; nt++) {
            int col = nt * 16 + row;
            if (col > 195) col = 195;
            bf16x8 bfv = *(const bf16x8*)(xb + (size_t)col * 1536 + kk * 32);
            acc[nt] = __builtin_amdgcn_mfma_f32_16x16x32_bf16(af, bfv, acc[nt], 0, 0, 0);
        }
    }
#pragma unroll
    for (int r = 0; r < 4; r++) {
        int o = o0 + grp * 4 + r;
        float sc = ldf(g, o, f) * rsqrtf(ldf(vv, o, f) + 1e-5f);
        float sh = ldf(bb, o, f) - ldf(mm, o, f) * sc;
#pragma unroll
        for (int nt = 0; nt < 13; nt++) {
            int col = nt * 16 + row;
            if (col >= NPIX) continue;
            float val = acc[nt][r] * sc + sh;
            size_t oidx = ((size_t)gb * 384 + o) * NPIX + col;
            if (f) ((float*)out)[oidx] = val;
            else ((bf16*)out)[oidx] = (bf16)val;
        }
    }
}

extern "C" void kernel_launch(void* const* d_in, const int* in_sizes, int n_in,
                              void* d_out, int out_size, void* d_ws, size_t ws_size,
                              hipStream_t stream) {
    const void* x      = d_in[0];
    const void* qkv_w  = d_in[1];
    const void* qkv_g  = d_in[2];
    const void* qkv_b  = d_in[3];
    const void* qkv_m  = d_in[4];
    const void* qkv_v  = d_in[5];
    const void* dw_w   = d_in[6];
    const void* dw_g   = d_in[7];
    const void* dw_b   = d_in[8];
    const void* dw_m   = d_in[9];
    const void* dw_v   = d_in[10];
    const void* proj_w = d_in[11];
    const void* proj_g = d_in[12];
    const void* proj_b = d_in[13];
    const void* proj_m = d_in[14];
    const void* proj_v = d_in[15];
    const void* ab     = d_in[16];
    const int*  idx    = (const int*)d_in[17];

    char* ws = (char*)d_ws;
    size_t off = 0;
    auto alloc = [&](size_t bytes) { void* p = ws + off; off += (bytes + 255) & ~(size_t)255; return p; };

    // fixed region
    int*   flag = (int*)alloc(4);
    bf16*  wq   = (bf16*)alloc((size_t)2304 * 384 * 2);
    bf16*  wp   = (bf16*)alloc((size_t)384 * 1536 * 2);
    bf16*  wd   = (bf16*)alloc((size_t)384 * 9 * 2);
    float* biasf= (float*)alloc((size_t)NHEADS * NPIX * NPIX * 4);
    size_t fixed = off;

    // per-image element strides (all 256B-aligned since *2 bytes are)
    const size_t s_xt = (size_t)NPIX * CIN;    // 75264
    const size_t s_qb = (size_t)384 * NPIX;    // 75264
    const size_t s_kt = (size_t)NPIX * 384;    // 75264
    const size_t s_vb = (size_t)1536 * MPAD;   // 344064
    const size_t s_ot = (size_t)NPIX * 1536;   // 301056
    const size_t per_image = (s_xt + s_qb + s_kt + s_vb + s_ot) * 2;  // bytes

    int CB = 128;
    while (CB > 1 && fixed + (size_t)CB * per_image > ws_size) CB >>= 1;

    bf16* xt  = (bf16*)alloc((size_t)CB * s_xt * 2);
    bf16* qb  = (bf16*)alloc((size_t)CB * s_qb * 2);
    bf16* ktp = (bf16*)alloc((size_t)CB * s_kt * 2);
    bf16* vb  = (bf16*)alloc((size_t)CB * s_vb * 2);
    bf16* ot  = (bf16*)alloc((size_t)CB * s_ot * 2);
    bf16* qt  = xt;  // xt dead after gemm_qkv; reuse for dwconv output

    detect_kernel<<<dim3(1), dim3(256), 0, stream>>>((const unsigned int*)x, flag);
    convert_kernel<<<dim3(256), dim3(256), 0, stream>>>(qkv_w, wq, 2304 * 384, flag);
    convert_kernel<<<dim3(256), dim3(256), 0, stream>>>(proj_w, wp, 384 * 1536, flag);
    convert_kernel<<<dim3(4), dim3(256), 0, stream>>>(dw_w, wd, 384 * 9, flag);
    int bg = (NHEADS * NPIX * NPIX + 255) / 256;
    bias_gather_kernel<<<dim3(bg), dim3(256), 0, stream>>>(ab, idx, flag, biasf);

    dim3 tb(32, 32);
    for (int b0 = 0; b0 < 128; b0 += CB) {
        int cb = (128 - b0 < CB) ? (128 - b0) : CB;
        transpose_x_kernel<<<dim3(7, 12, cb), tb, 0, stream>>>(x, flag, xt, b0);
        gemm_qkv_kernel<<<dim3(36, cb), dim3(256), 0, stream>>>(xt, wq, qkv_g, qkv_b, qkv_m, qkv_v,
                                                                flag, qb, ktp, vb);
        dwconv_kernel<<<dim3(7, 12, cb), tb, 0, stream>>>(qb, wd, dw_g, dw_b, dw_m, dw_v, flag, qt);
        attn_kernel<<<dim3(NHEADS, cb), dim3(256), 0, stream>>>(qt, ktp, vb, biasf, ot);
        gemm_proj_kernel<<<dim3(6, cb), dim3(256), 0, stream>>>(ot, wp, proj_g, proj_b, proj_m,
                                                                proj_v, flag, d_out, b0);
    }
}

// Round 3
// 596.070 us; speedup vs baseline: 1.8126x; 1.8126x over previous
//
#include <hip/hip_runtime.h>

typedef __bf16 bf16;
typedef bf16 bf16x8 __attribute__((ext_vector_type(8)));
typedef float f32x4 __attribute__((ext_vector_type(4)));

#define NPIX 196
#define CIN 384
#define NHEADS 12
#define MPAD 224

// flag-aware scalar load: f=1 -> fp32 data, f=0 -> bf16 data
__device__ __forceinline__ float ldf(const void* p, size_t i, int f) {
    return f ? ((const float*)p)[i] : (float)((const bf16*)p)[i];
}

// async global->LDS, 16B per lane. LDS dest must be wave-uniform base + lane*16.
__device__ __forceinline__ void gld16(const void* g, void* lds_wave_base) {
    __builtin_amdgcn_global_load_lds(
        (const __attribute__((address_space(1))) void*)(unsigned long long)g,
        (__attribute__((address_space(3))) void*)(unsigned long long)lds_wave_base,
        16, 0, 0);
}

// ---------------- dtype detector ----------------
__global__ void detect_kernel(const unsigned int* __restrict__ x, int* __restrict__ flag) {
    __shared__ int cnt;
    if (threadIdx.x == 0) cnt = 0;
    __syncthreads();
    int c = 0;
#pragma unroll
    for (int k = 0; k < 8; k++) {
        unsigned int w = x[threadIdx.x * 8 + k];
        unsigned int e = (w >> 7) & 0xFFu;
        if (e > 200u) c++;
    }
    atomicAdd(&cnt, c);
    __syncthreads();
    if (threadIdx.x == 0) *flag = (cnt >= 16) ? 1 : 0;
}

// ---------------- canonicalize weights to bf16 ----------------
__global__ void convert_kernel(const void* __restrict__ src, bf16* __restrict__ dst, int n,
                               const int* __restrict__ flag) {
    int f = *flag;
    for (int i = blockIdx.x * 256 + threadIdx.x; i < n; i += gridDim.x * 256)
        dst[i] = (bf16)ldf(src, i, f);
}

// ---------------- transpose x: (b, c, hw) -> (b, hw, c), canonical bf16 ----------------
__global__ void transpose_x_kernel(const void* __restrict__ x, const int* __restrict__ flag,
                                   bf16* __restrict__ xt, int b0) {
    __shared__ bf16 tile[32][33];
    int f = *flag;
    int b = blockIdx.z, gb = b0 + b;
    int c0 = blockIdx.y * 32;
    int hw0 = blockIdx.x * 32;
    int tx = threadIdx.x, ty = threadIdx.y;
    int hw = hw0 + tx, c = c0 + ty;
    if (hw < NPIX) tile[ty][tx] = (bf16)ldf(x, ((size_t)gb * CIN + c) * NPIX + hw, f);
    __syncthreads();
    int hw2 = hw0 + ty, c2 = c0 + tx;
    if (hw2 < NPIX) xt[((size_t)b * NPIX + hw2) * CIN + c2] = tile[tx][ty];
}

// ---------------- m97-style 128x128 GEMM mainloop ----------------
// A: [.. x K] row-major (weight rows), B: [.. x K] row-major (activation rows = B^T GEMM)
// As/Bs: 128*64 bf16 each. acc[mt][nt] covers (wm*64+mt*16) x (wn*64+nt*16).
// LDS chunk swizzle: slot (row, c) holds global chunk (row, c ^ (row&7)).
__device__ __forceinline__ void gemm_tile(const bf16* __restrict__ A, const bf16* __restrict__ B,
                                          int K, bf16* As, bf16* Bs, f32x4 acc[4][4]) {
    int tid = threadIdx.x;
    int wave = tid >> 6, lane = tid & 63;
    int wm = wave >> 1, wn = wave & 1;
    int row = lane & 15, grp = lane >> 4;
    int sr = lane >> 3;       // staged row within 8-row group == row&7 at staging
    int scg = (lane & 7) ^ sr;  // swizzled global chunk column
    const bf16* Ag = A + (size_t)(wave * 8 + sr) * K + scg * 8;
    const bf16* Bg = B + (size_t)(wave * 8 + sr) * K + scg * 8;
    for (int kb = 0; kb < K; kb += 64) {
        __syncthreads();
#pragma unroll
        for (int p = 0; p < 4; p++) {
            gld16(Ag + (size_t)(p * 32) * K + kb, As + (p * 256 + wave * 64) * 8);
            gld16(Bg + (size_t)(p * 32) * K + kb, Bs + (p * 256 + wave * 64) * 8);
        }
        __syncthreads();
#pragma unroll
        for (int ki = 0; ki < 2; ki++) {
            bf16x8 af[4], bfr[4];
#pragma unroll
            for (int t = 0; t < 4; t++) {
                int ra = wm * 64 + t * 16 + row;
                af[t] = *(const bf16x8*)(As + ra * 64 + (((ki * 4 + grp) ^ (ra & 7)) * 8));
                int rb = wn * 64 + t * 16 + row;
                bfr[t] = *(const bf16x8*)(Bs + rb * 64 + (((ki * 4 + grp) ^ (rb & 7)) * 8));
            }
#pragma unroll
            for (int mt = 0; mt < 4; mt++)
#pragma unroll
                for (int nt = 0; nt < 4; nt++)
                    acc[mt][nt] =
                        __builtin_amdgcn_mfma_f32_16x16x32_bf16(af[mt], bfr[nt], acc[mt][nt], 0, 0, 0);
        }
    }
}

// ---------------- QKV GEMM + BN, routed outputs ----------------
__global__ __launch_bounds__(256) void gemm_qkv_kernel(
    const bf16* __restrict__ xt, const bf16* __restrict__ w,
    const void* __restrict__ g, const void* __restrict__ bb,
    const void* __restrict__ mm, const void* __restrict__ vv, const int* __restrict__ flag,
    bf16* __restrict__ qb, bf16* __restrict__ kt, bf16* __restrict__ vb) {
    __shared__ bf16 As[128 * 64];
    __shared__ bf16 Bs[128 * 64];
    f32x4 acc[4][4];
#pragma unroll
    for (int i = 0; i < 4; i++)
#pragma unroll
        for (int j = 0; j < 4; j++) acc[i][j] = (f32x4){0.f, 0.f, 0.f, 0.f};
    int m0 = blockIdx.x * 128, n0 = blockIdx.y * 128;
    gemm_tile(w + (size_t)m0 * CIN, xt + (size_t)n0 * CIN, CIN, As, Bs, acc);
    int f = *flag;
    int wave = threadIdx.x >> 6, lane = threadIdx.x & 63;
    int wm = wave >> 1, wn = wave & 1, row = lane & 15, grp = lane >> 4;
#pragma unroll
    for (int mt = 0; mt < 4; mt++) {
#pragma unroll
        for (int r = 0; r < 4; r++) {
            int o = m0 + wm * 64 + mt * 16 + grp * 4 + r;
            float scv = ldf(g, o, f) * rsqrtf(ldf(vv, o, f) + 1e-5f);
            float sh = ldf(bb, o, f) - ldf(mm, o, f) * scv;
#pragma unroll
            for (int nt = 0; nt < 4; nt++) {
                int n = n0 + wn * 64 + nt * 16 + row;
                int b = n / NPIX, hw = n - b * NPIX;
                float val = acc[mt][nt][r] * scv + sh;
                bf16 bv = (bf16)val;
                if (o < 384) {
                    qb[((size_t)b * 384 + o) * NPIX + hw] = bv;
                } else if (o < 768) {
                    kt[((size_t)b * NPIX + hw) * CIN + (o - 384)] = bv;
                } else {
                    vb[((size_t)b * 1536 + (o - 768)) * MPAD + hw] = bv;
                }
            }
        }
    }
}

// ---------------- proj GEMM + BN -> output ----------------
__global__ __launch_bounds__(256) void gemm_proj_kernel(
    const bf16* __restrict__ ot, const bf16* __restrict__ w,
    const void* __restrict__ g, const void* __restrict__ bb,
    const void* __restrict__ mm, const void* __restrict__ vv, const int* __restrict__ flag,
    void* __restrict__ out, int b0) {
    __shared__ bf16 As[128 * 64];
    __shared__ bf16 Bs[128 * 64];
    f32x4 acc[4][4];
#pragma unroll
    for (int i = 0; i < 4; i++)
#pragma unroll
        for (int j = 0; j < 4; j++) acc[i][j] = (f32x4){0.f, 0.f, 0.f, 0.f};
    int m0 = blockIdx.x * 128, n0 = blockIdx.y * 128;
    gemm_tile(w + (size_t)m0 * 1536, ot + (size_t)n0 * 1536, 1536, As, Bs, acc);
    int f = *flag;
    int wave = threadIdx.x >> 6, lane = threadIdx.x & 63;
    int wm = wave >> 1, wn = wave & 1, row = lane & 15, grp = lane >> 4;
#pragma unroll
    for (int mt = 0; mt < 4; mt++) {
#pragma unroll
        for (int r = 0; r < 4; r++) {
            int o = m0 + wm * 64 + mt * 16 + grp * 4 + r;
            float scv = ldf(g, o, f) * rsqrtf(ldf(vv, o, f) + 1e-5f);
            float sh = ldf(bb, o, f) - ldf(mm, o, f) * scv;
#pragma unroll
            for (int nt = 0; nt < 4; nt++) {
                int n = n0 + wn * 64 + nt * 16 + row;
                int b = n / NPIX, hw = n - b * NPIX;
                float val = acc[mt][nt][r] * scv + sh;
                size_t oidx = ((size_t)(b0 + b) * 384 + o) * NPIX + hw;
                if (f) ((float*)out)[oidx] = val;
                else ((bf16*)out)[oidx] = (bf16)val;
            }
        }
    }
}

// ---------------- depthwise 3x3 conv + BN, write transposed (b, hw, c) ----------------
__global__ void dwconv_kernel(const bf16* __restrict__ qb, const bf16* __restrict__ w,
                              const void* __restrict__ g, const void* __restrict__ bb,
                              const void* __restrict__ mm, const void* __restrict__ vv,
                              const int* __restrict__ flag, bf16* __restrict__ qt) {
    __shared__ bf16 tile[32][33];
    int f = *flag;
    int b = blockIdx.z;
    int c0 = blockIdx.y * 32, hw0 = blockIdx.x * 32;
    int tx = threadIdx.x, ty = threadIdx.y;
    int c = c0 + ty, hw = hw0 + tx;
    if (hw < NPIX) {
        int y = hw / 14, x = hw % 14;
        float acc = 0.f;
        const bf16* wp = w + c * 9;
        const bf16* qp = qb + ((size_t)b * 384 + c) * NPIX;
#pragma unroll
        for (int ky = 0; ky < 3; ky++) {
            int yy = y + ky - 1;
            if (yy < 0 || yy >= 14) continue;
#pragma unroll
            for (int kx = 0; kx < 3; kx++) {
                int xx = x + kx - 1;
                if (xx < 0 || xx >= 14) continue;
                acc += (float)qp[yy * 14 + xx] * (float)wp[ky * 3 + kx];
            }
        }
        float sc = ldf(g, c, f) * rsqrtf(ldf(vv, c, f) + 1e-5f);
        float sh = ldf(bb, c, f) - ldf(mm, c, f) * sc;
        tile[ty][tx] = (bf16)(acc * sc + sh);
    }
    __syncthreads();
    int hw2 = hw0 + ty, c2 = c0 + tx;
    if (hw2 < NPIX) qt[((size_t)b * NPIX + hw2) * CIN + c2] = tile[tx][ty];
}

// ---------------- bias gather: (12,196,196) fp32 ----------------
__global__ void bias_gather_kernel(const void* __restrict__ ab, const int* __restrict__ idx,
                                   const int* __restrict__ flag, float* __restrict__ biasf) {
    int f = *flag;
    int t = blockIdx.x * 256 + threadIdx.x;
    if (t >= NHEADS * NPIX * NPIX) return;
    int h = t / (NPIX * NPIX);
    int rem = t - h * (NPIX * NPIX);
    biasf[t] = ldf(ab, h * NPIX + idx[rem], f);
}

// ---------------- attention per (b,h) ----------------
__global__ __launch_bounds__(256) void attn_kernel(
    const bf16* __restrict__ qt, const bf16* __restrict__ ktp, const bf16* __restrict__ vb,
    const float* __restrict__ biasf, bf16* __restrict__ ot) {
    __shared__ bf16 Ksh[MPAD * 32];
    __shared__ bf16 Pw[4][16 * MPAD];
    int h = blockIdx.x, b = blockIdx.y;
    int tid = threadIdx.x;
    int wave = tid >> 6, lane = tid & 63;
    int row = lane & 15, grp = lane >> 4;
    {
        int mrow = tid >> 2, chunk = tid & 3;
#pragma unroll
        for (int p = 0; p < 4; p++) {
            int mth = p * 64 + mrow;
            if (mth < NPIX) {
                *(bf16x8*)(Ksh + mth * 32 + chunk * 8) =
                    *(const bf16x8*)(ktp + ((size_t)b * NPIX + mth) * CIN + h * 32 + chunk * 8);
            } else if (mth < MPAD) {
                bf16x8 z;
#pragma unroll
                for (int i = 0; i < 8; i++) z[i] = (bf16)0.f;
                *(bf16x8*)(Ksh + mth * 32 + chunk * 8) = z;
            }
        }
    }
    __syncthreads();
    const float scale = 0.17677669529663687f;
    f32x4 zf = {0.f, 0.f, 0.f, 0.f};
    for (int nb = wave; nb < 13; nb += 4) {
        int n0 = nb * 16;
        int qrow = n0 + row;
        if (qrow > 195) qrow = 195;
        bf16x8 aq = *(const bf16x8*)(qt + ((size_t)b * NPIX + qrow) * CIN + h * 32 + grp * 8);
        f32x4 sacc[14];
#pragma unroll
        for (int mt = 0; mt < 14; mt++) {
            bf16x8 bk = *(const bf16x8*)(Ksh + (mt * 16 + row) * 32 + grp * 8);
            sacc[mt] = __builtin_amdgcn_mfma_f32_16x16x32_bf16(aq, bk, zf, 0, 0, 0);
        }
#pragma unroll
        for (int r = 0; r < 4; r++) {
            int n = n0 + grp * 4 + r;
            int nc = n > 195 ? 195 : n;
            const float* bp = biasf + ((size_t)h * NPIX + nc) * NPIX;
            float sv[14];
            float mx = -3.4e38f;
#pragma unroll
            for (int mt = 0; mt < 14; mt++) {
                int col = mt * 16 + row;
                float bias = (col < NPIX) ? bp[col] : -3.0e38f;
                float s = sacc[mt][r] * scale + bias;
                sv[mt] = s;
                mx = fmaxf(mx, s);
            }
            mx = fmaxf(mx, __shfl_xor(mx, 1));
            mx = fmaxf(mx, __shfl_xor(mx, 2));
            mx = fmaxf(mx, __shfl_xor(mx, 4));
            mx = fmaxf(mx, __shfl_xor(mx, 8));
            float sum = 0.f;
#pragma unroll
            for (int mt = 0; mt < 14; mt++) {
                float e = __expf(sv[mt] - mx);
                sv[mt] = e;
                sum += e;
            }
            sum += __shfl_xor(sum, 1);
            sum += __shfl_xor(sum, 2);
            sum += __shfl_xor(sum, 4);
            sum += __shfl_xor(sum, 8);
            float inv = 1.f / sum;
#pragma unroll
            for (int mt = 0; mt < 14; mt++) {
                Pw[wave][(grp * 4 + r) * MPAD + mt * 16 + row] = (bf16)(sv[mt] * inv);
            }
        }
        f32x4 oacc[8];
#pragma unroll
        for (int dt = 0; dt < 8; dt++) oacc[dt] = zf;
#pragma unroll
        for (int kt = 0; kt < 7; kt++) {
            bf16x8 ap = *(const bf16x8*)(&Pw[wave][row * MPAD + kt * 32 + grp * 8]);
#pragma unroll
            for (int dt = 0; dt < 8; dt++) {
                bf16x8 bv = *(const bf16x8*)(vb + ((size_t)b * 1536 + h * 128 + dt * 16 + row) * MPAD +
                                             kt * 32 + grp * 8);
                oacc[dt] = __builtin_amdgcn_mfma_f32_16x16x32_bf16(ap, bv, oacc[dt], 0, 0, 0);
            }
        }
#pragma unroll
        for (int dt = 0; dt < 8; dt++) {
#pragma unroll
            for (int r = 0; r < 4; r++) {
                int n = n0 + grp * 4 + r;
                if (n < NPIX) {
                    float val = oacc[dt][r];
                    val = val > 0.f ? val : 0.f;
                    ot[((size_t)b * NPIX + n) * 1536 + h * 128 + dt * 16 + row] = (bf16)val;
                }
            }
        }
    }
}

extern "C" void kernel_launch(void* const* d_in, const int* in_sizes, int n_in,
                              void* d_out, int out_size, void* d_ws, size_t ws_size,
                              hipStream_t stream) {
    const void* x      = d_in[0];
    const void* qkv_w  = d_in[1];
    const void* qkv_g  = d_in[2];
    const void* qkv_b  = d_in[3];
    const void* qkv_m  = d_in[4];
    const void* qkv_v  = d_in[5];
    const void* dw_w   = d_in[6];
    const void* dw_g   = d_in[7];
    const void* dw_b   = d_in[8];
    const void* dw_m   = d_in[9];
    const void* dw_v   = d_in[10];
    const void* proj_w = d_in[11];
    const void* proj_g = d_in[12];
    const void* proj_b = d_in[13];
    const void* proj_m = d_in[14];
    const void* proj_v = d_in[15];
    const void* ab     = d_in[16];
    const int*  idx    = (const int*)d_in[17];

    char* ws = (char*)d_ws;
    size_t off = 0;
    auto alloc = [&](size_t bytes) { void* p = ws + off; off += (bytes + 255) & ~(size_t)255; return p; };

    int*   flag = (int*)alloc(4);
    bf16*  wq   = (bf16*)alloc((size_t)2304 * 384 * 2);
    bf16*  wp   = (bf16*)alloc((size_t)384 * 1536 * 2);
    bf16*  wd   = (bf16*)alloc((size_t)384 * 9 * 2);
    float* biasf= (float*)alloc((size_t)NHEADS * NPIX * NPIX * 4);
    size_t fixed = off;

    const size_t s_xt = (size_t)NPIX * CIN;
    const size_t s_qb = (size_t)384 * NPIX;
    const size_t s_kt = (size_t)NPIX * 384;
    const size_t s_vb = (size_t)1536 * MPAD;
    const size_t s_ot = (size_t)NPIX * 1536;
    const size_t per_image = (s_xt + s_qb + s_kt + s_vb + s_ot) * 2;

    int CB = 128;
    while (CB > 32 && fixed + (size_t)CB * per_image > ws_size) CB >>= 1;

    bf16* xt  = (bf16*)alloc((size_t)CB * s_xt * 2);
    bf16* qb  = (bf16*)alloc((size_t)CB * s_qb * 2);
    bf16* ktp = (bf16*)alloc((size_t)CB * s_kt * 2);
    bf16* vb  = (bf16*)alloc((size_t)CB * s_vb * 2);
    bf16* ot  = (bf16*)alloc((size_t)CB * s_ot * 2);
    bf16* qt  = xt;  // xt dead after gemm_qkv; reuse for dwconv output

    detect_kernel<<<dim3(1), dim3(256), 0, stream>>>((const unsigned int*)x, flag);
    convert_kernel<<<dim3(256), dim3(256), 0, stream>>>(qkv_w, wq, 2304 * 384, flag);
    convert_kernel<<<dim3(256), dim3(256), 0, stream>>>(proj_w, wp, 384 * 1536, flag);
    convert_kernel<<<dim3(4), dim3(256), 0, stream>>>(dw_w, wd, 384 * 9, flag);
    int bg = (NHEADS * NPIX * NPIX + 255) / 256;
    bias_gather_kernel<<<dim3(bg), dim3(256), 0, stream>>>(ab, idx, flag, biasf);

    dim3 tb(32, 32);
    for (int b0 = 0; b0 < 128; b0 += CB) {
        int cb = (128 - b0 < CB) ? (128 - b0) : CB;
        int ntiles = (cb * NPIX) / 128;  // cb in {32,64,128} -> exact
        transpose_x_kernel<<<dim3(7, 12, cb), tb, 0, stream>>>(x, flag, xt, b0);
        gemm_qkv_kernel<<<dim3(18, ntiles), dim3(256), 0, stream>>>(xt, wq, qkv_g, qkv_b, qkv_m,
                                                                    qkv_v, flag, qb, ktp, vb);
        dwconv_kernel<<<dim3(7, 12, cb), tb, 0, stream>>>(qb, wd, dw_g, dw_b, dw_m, dw_v, flag, qt);
        attn_kernel<<<dim3(NHEADS, cb), dim3(256), 0, stream>>>(qt, ktp, vb, biasf, ot);
        gemm_proj_kernel<<<dim3(3, ntiles), dim3(256), 0, stream>>>(ot, wp, proj_g, proj_b, proj_m,
                                                                    proj_v, flag, d_out, b0);
    }
}